// Round 1
// baseline (1332.352 us; speedup 1.0000x reference)
//
#include <hip/hip_runtime.h>

#define BATCH    32
#define CHANNELS 2048
#define SIZE     4096

constexpr int BX  = 64;          // threads along s (each does float4 -> 256 floats/block)
constexpr int BY  = 8;           // channel chunks per block
constexpr int VEC = 4;
constexpr int S_PER_BLOCK = BX * VEC;       // 256
constexpr int C_PER_Y     = CHANNELS / BY;  // 256

__global__ __launch_bounds__(BX * BY)
void CWG_82214263980322_kernel(const float* __restrict__ x,
                               const float* __restrict__ w,
                               const float* __restrict__ bias,
                               float* __restrict__ out)
{
    __shared__ float4 smem[BY][BX];

    const int tx = threadIdx.x;        // 0..63
    const int ty = threadIdx.y;        // 0..7
    const int s_tile = blockIdx.x;     // 0..15
    const int b = blockIdx.y;          // 0..31

    const int s = s_tile * S_PER_BLOCK + tx * VEC;

    // float4-typed pointers; stride between channels is SIZE/4 float4s
    const float4* xp = reinterpret_cast<const float4*>(
        x + (size_t)b * CHANNELS * SIZE + (size_t)ty * C_PER_Y * SIZE + s);
    const float4* wp = reinterpret_cast<const float4*>(
        w + (size_t)ty * C_PER_Y * SIZE + s);

    float4 acc = make_float4(0.f, 0.f, 0.f, 0.f);

    #pragma unroll 8
    for (int c = 0; c < C_PER_Y; ++c) {
        const float4 xv = xp[(size_t)c * (SIZE / VEC)];
        const float4 wv = wp[(size_t)c * (SIZE / VEC)];
        acc.x = fmaf(xv.x, wv.x, acc.x);
        acc.y = fmaf(xv.y, wv.y, acc.y);
        acc.z = fmaf(xv.z, wv.z, acc.z);
        acc.w = fmaf(xv.w, wv.w, acc.w);
    }

    smem[ty][tx] = acc;
    __syncthreads();

    if (ty == 0) {
        float4 t = smem[0][tx];
        #pragma unroll
        for (int j = 1; j < BY; ++j) {
            const float4 u = smem[j][tx];
            t.x += u.x; t.y += u.y; t.z += u.z; t.w += u.w;
        }
        const float4 bv = *reinterpret_cast<const float4*>(bias + s);
        t.x = fmaxf(t.x + bv.x, 0.f);
        t.y = fmaxf(t.y + bv.y, 0.f);
        t.z = fmaxf(t.z + bv.z, 0.f);
        t.w = fmaxf(t.w + bv.w, 0.f);
        *reinterpret_cast<float4*>(out + (size_t)b * SIZE + s) = t;
    }
}

extern "C" void kernel_launch(void* const* d_in, const int* in_sizes, int n_in,
                              void* d_out, int out_size, void* d_ws, size_t ws_size,
                              hipStream_t stream) {
    const float* x    = (const float*)d_in[0];  // [32, 2048, 4096]
    const float* w    = (const float*)d_in[1];  // [2048, 4096]
    const float* bias = (const float*)d_in[2];  // [4096]
    float* out        = (float*)d_out;          // [32, 4096]

    dim3 grid(SIZE / S_PER_BLOCK, BATCH);       // (16, 32)
    dim3 block(BX, BY);                         // 512 threads
    CWG_82214263980322_kernel<<<grid, block, 0, stream>>>(x, w, bias, out);
}

// Round 2
// 1331.401 us; speedup vs baseline: 1.0007x; 1.0007x over previous
//
#include <hip/hip_runtime.h>

#define BATCH    32
#define CHANNELS 2048
#define SIZE     4096

typedef float v4f __attribute__((ext_vector_type(4)));

constexpr int BX    = 64;                 // threads along s (float4 each)
constexpr int BY    = 4;                  // c-slices per block (one per wave)
constexpr int NB    = 4;                  // batches per block
constexpr int CCH   = 8;                  // channel chunks across blocks
constexpr int CBLK  = CHANNELS / CCH;     // 256 channels per block
constexpr int CW    = CBLK / BY;          // 64 channels per wave
constexpr int SPB   = BX * 4;             // 256 floats of s per block
constexpr int STILES = SIZE / SPB;        // 16
constexpr int BG    = BATCH / NB;         // 8 batch groups
constexpr int TILES = STILES * CCH;       // 128 (s,cc) tiles; bg stride = 128 ≡ 0 mod 8 → same XCD

// Phase 1: partial[cc][b][s] = sum over the cc-th channel chunk of x[b,c,s]*w[c,s]
__global__ __launch_bounds__(BX * BY)
void CWG_k1(const float* __restrict__ x,
            const float* __restrict__ w,
            float* __restrict__ partial)
{
    __shared__ v4f smem[NB][BY][BX];

    const int tx = threadIdx.x;
    const int ty = threadIdx.y;
    const int id = blockIdx.x;
    const int bg   = id / TILES;          // 0..7  (slow: same-tile blocks land on same XCD)
    const int tile = id % TILES;
    const int cc   = tile / STILES;       // 0..7
    const int st   = tile % STILES;       // 0..15

    const int s  = st * SPB + tx * 4;
    const int c0 = cc * CBLK + ty * CW;
    const int b0 = bg * NB;

    const float* wp = w + (size_t)c0 * SIZE + s;
    const float* xp = x + ((size_t)b0 * CHANNELS + (size_t)c0) * SIZE + s;

    v4f acc[NB];
    #pragma unroll
    for (int nb = 0; nb < NB; ++nb) acc[nb] = (v4f)(0.f);

    #pragma unroll 4
    for (int c = 0; c < CW; ++c) {
        const v4f wv = *reinterpret_cast<const v4f*>(wp + (size_t)c * SIZE);
        #pragma unroll
        for (int nb = 0; nb < NB; ++nb) {
            const v4f xv = __builtin_nontemporal_load(
                reinterpret_cast<const v4f*>(
                    xp + ((size_t)nb * CHANNELS + (size_t)c) * SIZE));
            acc[nb] = xv * wv + acc[nb];   // contracts to v_fma per lane
        }
    }

    #pragma unroll
    for (int nb = 0; nb < NB; ++nb) smem[nb][ty][tx] = acc[nb];
    __syncthreads();

    // BY == NB: thread (tx,ty) reduces batch index ty across the BY c-slices
    v4f t = smem[ty][0][tx] + smem[ty][1][tx] + smem[ty][2][tx] + smem[ty][3][tx];
    const int b = b0 + ty;
    *reinterpret_cast<v4f*>(partial + ((size_t)cc * BATCH + b) * SIZE + s) = t;
}

// Phase 2: out[b][s] = relu(bias[s] + sum_cc partial[cc][b][s])
__global__ __launch_bounds__(256)
void CWG_k2(const float* __restrict__ partial,
            const float* __restrict__ bias,
            float* __restrict__ out)
{
    const int t  = blockIdx.x * blockDim.x + threadIdx.x;  // 0 .. 32*1024-1
    const int b  = t >> 10;
    const int s  = (t & 1023) * 4;

    v4f sum = *reinterpret_cast<const v4f*>(bias + s);
    #pragma unroll
    for (int cc = 0; cc < CCH; ++cc)
        sum += *reinterpret_cast<const v4f*>(partial + ((size_t)cc * BATCH + b) * SIZE + s);

    v4f r;
    r.x = fmaxf(sum.x, 0.f);
    r.y = fmaxf(sum.y, 0.f);
    r.z = fmaxf(sum.z, 0.f);
    r.w = fmaxf(sum.w, 0.f);
    *reinterpret_cast<v4f*>(out + (size_t)b * SIZE + s) = r;
}

extern "C" void kernel_launch(void* const* d_in, const int* in_sizes, int n_in,
                              void* d_out, int out_size, void* d_ws, size_t ws_size,
                              hipStream_t stream) {
    const float* x    = (const float*)d_in[0];  // [32, 2048, 4096]
    const float* w    = (const float*)d_in[1];  // [2048, 4096]
    const float* bias = (const float*)d_in[2];  // [4096]
    float* out        = (float*)d_out;          // [32, 4096]
    float* partial    = (float*)d_ws;           // [CCH, 32, 4096] = 4 MiB, fully overwritten

    CWG_k1<<<dim3(BG * TILES), dim3(BX, BY), 0, stream>>>(x, w, partial);

    const int n2 = BATCH * SIZE / 4;            // 32768 float4 outputs
    CWG_k2<<<dim3(n2 / 256), dim3(256), 0, stream>>>(partial, bias, out);
}